// Round 2
// baseline (162.938 us; speedup 1.0000x reference)
//
#include <hip/hip_runtime.h>
#include <math.h>

// loss = ALPHA * mean(level_w * (softplus(x) - x*t))
//      + BETA  * sum_{b,e} relu(sig(x[b,dst]) - sig(x[b,src])) / (B*N)
//
// R7: producer/consumer wave specialization + conflict-free swizzled P.
// 256 blocks (1/CU) x 1024 threads. Waves 0-7 (producers) load+transform
// group k+1 into P[(k+1)&1] while waves 8-15 (consumers) gather edges of
// group k from P[k&1]. Overlap is structural (separate waves own VMEM vs
// LDS pipes) -- immune to the load-sinking that killed the R6 pipeline.
// P layout is XOR-swizzled (node n -> slot n ^ ((n>>4)&3)) which makes the
// transposed h4 writes exactly 4-accesses-per-bank (the ds_write_b64
// minimum), eliminating the 16-way write conflicts (~2M of the 2.87M
// SQ_LDS_BANK_CONFLICT cycles). Gathers apply the same bijection.

#define ALPHA_C 1.0f
#define BETA_C  0.5f

constexpr int B = 4096;
constexpr int N = 4096;
constexpr int E = 16384;
constexpr int THREADS = 1024;
constexpr int GRID = 256;             // 1 block per CU
constexpr int R = 4;                  // rows per group (h4 gather width)
constexpr int ROWS_PB = B / GRID;     // 16 rows per block
constexpr int GPB = ROWS_PB / R;      // 4 groups per block
constexpr int PTHREADS = 512;         // producer threads (waves 0-7)
constexpr int CTHREADS = THREADS - PTHREADS;  // consumer threads (waves 8-15)
constexpr int CPT = (N / 4) / PTHREADS;       // 2 float4-cols per producer
constexpr int EPC = E / 4 / CTHREADS;         // 8 int4-pairs per consumer

typedef _Float16 h4 __attribute__((ext_vector_type(4)));

__global__ __launch_bounds__(64) void init_out_kernel(float* out) {
    if (threadIdx.x == 0) out[0] = 0.0f;
}

__device__ __forceinline__ void fast_sig_sp(float x, float& p, float& sp) {
    // q = exp(-|x|) in (0,1]; both sigmoid and softplus from one exp
    float q = __expf(-fabsf(x));
    float d = 1.0f + q;
    float r = __builtin_amdgcn_rcpf(d);     // ~1 ulp approx reciprocal
    p  = (x >= 0.0f) ? r : q * r;           // sigmoid
    sp = fmaxf(x, 0.0f) + __logf(d);        // softplus = max(x,0)+log(1+q)
}

// node n -> LDS slot; bijective, makes transposed writes bank-uniform
__device__ __forceinline__ int swz(int n) { return n ^ ((n >> 4) & 3); }

__global__ __launch_bounds__(THREADS, 4) void hier_loss_kernel(
    const float* __restrict__ outputs,
    const float* __restrict__ targets,
    const float* __restrict__ level_w,
    const int*   __restrict__ edge_src,
    const int*   __restrict__ edge_dst,
    float*       __restrict__ out)
{
    __shared__ h4 P[2][N];          // 64 KB, double-buffered swizzled fp16 P

    const int tid  = threadIdx.x;
    const int row0 = blockIdx.x * ROWS_PB;

    float s1 = 0.0f, s2 = 0.0f;

    if (tid < PTHREADS) {
        // ---------------- producers: waves 0-7 ----------------
        const float4* out4 = (const float4*)outputs;
        const float4* tgt4 = (const float4*)targets;
        const float4* lw4  = (const float4*)level_w;

        float wv[CPT][4];
#pragma unroll
        for (int c = 0; c < CPT; ++c) {
            const float4 w = lw4[tid + c * PTHREADS];
            wv[c][0] = w.x; wv[c][1] = w.y; wv[c][2] = w.z; wv[c][3] = w.w;
        }
        const int kx = (tid >> 2) & 3;      // write-slot XOR key = (n>>4)&3

        for (int step = 0; step < GPB + 1; ++step) {
            if (step < GPB) {
                // batch all 16 loads (in flight together), then transform
                float4 xs[CPT][R], ts[CPT][R];
#pragma unroll
                for (int c = 0; c < CPT; ++c)
#pragma unroll
                for (int r = 0; r < R; ++r) {
                    const size_t idx =
                        (size_t)(row0 + step * R + r) * (N / 4) + tid + c * PTHREADS;
                    xs[c][r] = out4[idx];
                    ts[c][r] = tgt4[idx];
                }
                h4* Pb = P[step & 1];
#pragma unroll
                for (int c = 0; c < CPT; ++c) {
                    h4 tmp[4];      // tmp[k][r] = p(row r, node 4*col+k)
#pragma unroll
                    for (int r = 0; r < R; ++r) {
                        const float xv[4] = {xs[c][r].x, xs[c][r].y, xs[c][r].z, xs[c][r].w};
                        const float tv[4] = {ts[c][r].x, ts[c][r].y, ts[c][r].z, ts[c][r].w};
#pragma unroll
                        for (int k = 0; k < 4; ++k) {
                            float p, sp;
                            fast_sig_sp(xv[k], p, sp);
                            s1 = fmaf(wv[c][k], sp - xv[k] * tv[k], s1);
                            tmp[k][r] = (_Float16)p;
                        }
                    }
                    const int base = 4 * (tid + c * PTHREADS);
#pragma unroll
                    for (int k = 0; k < 4; ++k) Pb[base + (k ^ kx)] = tmp[k];
                }
            }
            __syncthreads();
        }
    } else {
        // ---------------- consumers: waves 8-15 ----------------
        const int ct = tid - PTHREADS;
        const int4* es4 = (const int4*)edge_src;
        const int4* ed4 = (const int4*)edge_dst;

        // hoist edge indices into registers during the prologue step
        int4 se[EPC], de[EPC];
#pragma unroll
        for (int j = 0; j < EPC; ++j) {
            se[j] = es4[ct + j * CTHREADS];
            de[j] = ed4[ct + j * CTHREADS];
        }

        for (int step = 0; step < GPB + 1; ++step) {
            if (step >= 1) {
                const h4* Pc = P[(step - 1) & 1];
                h4 acc0 = {0, 0, 0, 0};
                h4 acc1 = {0, 0, 0, 0};
                const h4 zero = {0, 0, 0, 0};
#pragma unroll
                for (int j = 0; j < EPC; ++j) {
                    const int4 s = se[j];
                    const int4 d = de[j];
                    h4 a0 = Pc[swz(s.x)], c0 = Pc[swz(d.x)];
                    h4 a1 = Pc[swz(s.y)], c1 = Pc[swz(d.y)];
                    h4 a2 = Pc[swz(s.z)], c2 = Pc[swz(d.z)];
                    h4 a3 = Pc[swz(s.w)], c3 = Pc[swz(d.w)];
                    acc0 += __builtin_elementwise_max(c0 - a0, zero);   // v_pk_*
                    acc1 += __builtin_elementwise_max(c1 - a1, zero);
                    acc0 += __builtin_elementwise_max(c2 - a2, zero);
                    acc1 += __builtin_elementwise_max(c3 - a3, zero);
                }
#pragma unroll
                for (int l = 0; l < 4; ++l) s2 += (float)acc0[l] + (float)acc1[l];
            }
            __syncthreads();
        }
    }

    // ---- block reduce: wave64 shuffle, cross-wave via reused LDS ----
#pragma unroll
    for (int off = 32; off > 0; off >>= 1) {
        s1 += __shfl_down(s1, off, 64);
        s2 += __shfl_down(s2, off, 64);
    }
    float* red = (float*)P;              // safe: role loops end with a barrier
    const int wave = tid >> 6;           // 16 waves
    const int lane = tid & 63;
    if (lane == 0) { red[wave] = s1; red[16 + wave] = s2; }
    __syncthreads();
    if (tid == 0) {
        float a = 0.0f, c = 0.0f;
#pragma unroll
        for (int v = 0; v < 16; ++v) { a += red[v]; c += red[16 + v]; }
        const float inv = 1.0f / ((float)B * (float)N);
        atomicAdd(out, (ALPHA_C * a + BETA_C * c) * inv);
    }
}

extern "C" void kernel_launch(void* const* d_in, const int* in_sizes, int n_in,
                              void* d_out, int out_size, void* d_ws, size_t ws_size,
                              hipStream_t stream) {
    const float* outputs = (const float*)d_in[0];
    const float* targets = (const float*)d_in[1];
    const float* level_w = (const float*)d_in[2];
    const int*   edge_src = (const int*)d_in[3];
    const int*   edge_dst = (const int*)d_in[4];
    float* out = (float*)d_out;

    init_out_kernel<<<1, 64, 0, stream>>>(out);
    hier_loss_kernel<<<GRID, THREADS, 0, stream>>>(outputs, targets, level_w,
                                                   edge_src, edge_dst, out);
}

// Round 3
// 155.110 us; speedup vs baseline: 1.0505x; 1.0505x over previous
//
#include <hip/hip_runtime.h>
#include <math.h>

// loss = ALPHA * mean(level_w * (softplus(x) - x*t))
//      + BETA  * sum_{b,e} relu(sig(x[b,dst]) - sig(x[b,src])) / (B*N)
//
// R8: pinned software pipeline. 256 blocks (1/CU) x 1024 threads, 4 row-
// groups per block, double-buffered P (2x32 KB LDS). Per step:
//   {issue next group's 8 global loads} sched_barrier(0)
//   {all edge gathers on current buffer (LDS-only)} sched_barrier(0)
//   {transform landed registers -> other buffer} __syncthreads
// The sched_barrier(0) pins stop hipcc from sinking the loads to their
// use point (R6: VGPR=52 proved the prefetch was compiled away; R5/R6/R7
// all executed phase-serialized at 47-55 us). Loads now stream during the
// gather phase by construction. Edge indices are cached in VGPRs so the
// step body has no stray vmem ops (clean vmcnt accounting). No LDS
// swizzle: R7 showed write conflicts are minor (2.87M->2.61M) and the
// gather-side XOR costs more VALU than it saves.

#define ALPHA_C 1.0f
#define BETA_C  0.5f

constexpr int B = 4096;
constexpr int N = 4096;
constexpr int E = 16384;
constexpr int THREADS = 1024;
constexpr int GRID = 256;             // 1 block per CU
constexpr int R = 4;                  // rows per group (h4 gather width)
constexpr int ROWS_PB = B / GRID;     // 16 rows per block
constexpr int GPB = ROWS_PB / R;      // 4 groups (pipeline steps) per block
constexpr int EPC = E / 4 / THREADS;  // 4 int4-pairs per thread per step

typedef _Float16 h4 __attribute__((ext_vector_type(4)));

__global__ __launch_bounds__(64) void init_out_kernel(float* out) {
    if (threadIdx.x == 0) out[0] = 0.0f;
}

__device__ __forceinline__ void fast_sig_sp(float x, float& p, float& sp) {
    // q = exp(-|x|) in (0,1]; both sigmoid and softplus from one exp
    float q = __expf(-fabsf(x));
    float d = 1.0f + q;
    float r = __builtin_amdgcn_rcpf(d);     // ~1 ulp approx reciprocal
    p  = (x >= 0.0f) ? r : q * r;           // sigmoid
    sp = fmaxf(x, 0.0f) + __logf(d);        // softplus = max(x,0)+log(1+q)
}

__global__ __launch_bounds__(THREADS, 4) void hier_loss_kernel(
    const float* __restrict__ outputs,
    const float* __restrict__ targets,
    const float* __restrict__ level_w,
    const int*   __restrict__ edge_src,
    const int*   __restrict__ edge_dst,
    float*       __restrict__ out)
{
    __shared__ h4 P[2][N];          // 64 KB, double-buffered fp16 sigmoid rows

    const int tid  = threadIdx.x;
    const int row0 = blockIdx.x * ROWS_PB;

    const float4* out4 = (const float4*)outputs;
    const float4* tgt4 = (const float4*)targets;
    const float4* lw4  = (const float4*)level_w;
    const int4*   es4  = (const int4*)edge_src;
    const int4*   ed4  = (const int4*)edge_dst;

    // one float4-column per thread (N/4 == THREADS), constant across groups
    const float4 w = lw4[tid];
    const float wv[4] = {w.x, w.y, w.z, w.w};

    // edge indices cached in VGPRs (32 regs): step body stays vmem-free
    int4 se[EPC], de[EPC];
#pragma unroll
    for (int j = 0; j < EPC; ++j) {
        se[j] = es4[tid + j * THREADS];
        de[j] = ed4[tid + j * THREADS];
    }

    float s1 = 0.0f, s2 = 0.0f;
    float4 xs[R], ts[R];

    // ---- prologue: load + transform group 0 into P[0] ----
#pragma unroll
    for (int r = 0; r < R; ++r) {
        const size_t idx = (size_t)(row0 + r) * (N / 4) + tid;
        xs[r] = out4[idx];
        ts[r] = tgt4[idx];
    }
    {
        h4 tmp[4];
#pragma unroll
        for (int r = 0; r < R; ++r) {
            const float xv[4] = {xs[r].x, xs[r].y, xs[r].z, xs[r].w};
            const float tv[4] = {ts[r].x, ts[r].y, ts[r].z, ts[r].w};
#pragma unroll
            for (int k = 0; k < 4; ++k) {
                float p, sp;
                fast_sig_sp(xv[k], p, sp);
                s1 = fmaf(wv[k], sp - xv[k] * tv[k], s1);
                tmp[k][r] = (_Float16)p;
            }
        }
#pragma unroll
        for (int k = 0; k < 4; ++k) P[0][4 * tid + k] = tmp[k];
    }
    __syncthreads();

    // ---- pinned pipeline: loads(k+1) stream under gathers(k) ----
#pragma unroll
    for (int kg = 0; kg < GPB; ++kg) {
        // (1) issue next group's global loads
        if (kg + 1 < GPB) {
#pragma unroll
            for (int r = 0; r < R; ++r) {
                const size_t idx = (size_t)(row0 + (kg + 1) * R + r) * (N / 4) + tid;
                xs[r] = out4[idx];
                ts[r] = tgt4[idx];
            }
        }
        __builtin_amdgcn_sched_barrier(0);   // pin: loads issued above

        // (2) edge gathers on current buffer; LDS-only, no vmcnt waits
        {
            const h4* Pc = P[kg & 1];
            h4 acc0 = {0, 0, 0, 0};
            h4 acc1 = {0, 0, 0, 0};
            const h4 zero = {0, 0, 0, 0};
#pragma unroll
            for (int j = 0; j < EPC; ++j) {
                const int4 s = se[j];
                const int4 d = de[j];
                h4 a0 = Pc[s.x], c0 = Pc[d.x];
                h4 a1 = Pc[s.y], c1 = Pc[d.y];
                h4 a2 = Pc[s.z], c2 = Pc[d.z];
                h4 a3 = Pc[s.w], c3 = Pc[d.w];
                acc0 += __builtin_elementwise_max(c0 - a0, zero);   // v_pk_*
                acc1 += __builtin_elementwise_max(c1 - a1, zero);
                acc0 += __builtin_elementwise_max(c2 - a2, zero);
                acc1 += __builtin_elementwise_max(c3 - a3, zero);
            }
#pragma unroll
            for (int l = 0; l < 4; ++l) s2 += (float)acc0[l] + (float)acc1[l];
        }
        __builtin_amdgcn_sched_barrier(0);   // pin: gathers before transform

        // (3) transform landed registers into the other buffer
        if (kg + 1 < GPB) {
            h4 tmp[4];
#pragma unroll
            for (int r = 0; r < R; ++r) {
                const float xv[4] = {xs[r].x, xs[r].y, xs[r].z, xs[r].w};
                const float tv[4] = {ts[r].x, ts[r].y, ts[r].z, ts[r].w};
#pragma unroll
                for (int k = 0; k < 4; ++k) {
                    float p, sp;
                    fast_sig_sp(xv[k], p, sp);
                    s1 = fmaf(wv[k], sp - xv[k] * tv[k], s1);
                    tmp[k][r] = (_Float16)p;
                }
            }
#pragma unroll
            for (int k = 0; k < 4; ++k) P[(kg + 1) & 1][4 * tid + k] = tmp[k];
        }
        __syncthreads();   // P[kg&1] reads done; P[(kg+1)&1] writes visible
    }

    // ---- block reduce: wave64 shuffle, cross-wave via reused LDS ----
#pragma unroll
    for (int off = 32; off > 0; off >>= 1) {
        s1 += __shfl_down(s1, off, 64);
        s2 += __shfl_down(s2, off, 64);
    }
    float* red = (float*)P;              // safe: loop ends with a barrier
    const int wave = tid >> 6;           // 16 waves
    const int lane = tid & 63;
    if (lane == 0) { red[wave] = s1; red[16 + wave] = s2; }
    __syncthreads();
    if (tid == 0) {
        float a = 0.0f, c = 0.0f;
#pragma unroll
        for (int v = 0; v < 16; ++v) { a += red[v]; c += red[16 + v]; }
        const float inv = 1.0f / ((float)B * (float)N);
        atomicAdd(out, (ALPHA_C * a + BETA_C * c) * inv);
    }
}

extern "C" void kernel_launch(void* const* d_in, const int* in_sizes, int n_in,
                              void* d_out, int out_size, void* d_ws, size_t ws_size,
                              hipStream_t stream) {
    const float* outputs = (const float*)d_in[0];
    const float* targets = (const float*)d_in[1];
    const float* level_w = (const float*)d_in[2];
    const int*   edge_src = (const int*)d_in[3];
    const int*   edge_dst = (const int*)d_in[4];
    float* out = (float*)d_out;

    init_out_kernel<<<1, 64, 0, stream>>>(out);
    hier_loss_kernel<<<GRID, THREADS, 0, stream>>>(outputs, targets, level_w,
                                                   edge_src, edge_dst, out);
}